// Round 1
// 957.145 us; speedup vs baseline: 1.0044x; 1.0044x over previous
//
#include <hip/hip_runtime.h>

// FiniteDifferenceGradient: periodic central difference on (4,256,256,256) f32.
// out[b][c][x][y][z], c in {gx, gy, gz}, spacing = 1 -> grad = (v[+1]-v[-1])*0.5
//
// Layout constants (float4-granular indices):
//   z4 stride 1 (64 per row), y stride 64 (<<6), x stride 16384 (<<14),
//   b stride 1<<22.
//
// V2 structure (vs V1 one-point-per-thread):
//   - Each thread owns fixed (b, y, z4) and marches 16 consecutive x values,
//     keeping v[x-1], v[x], v[x+1] in a sliding register window. The
//     256KiB-strided x-neighbor loads (worst L2 citizens) become register
//     moves; input planes are read once per thread column.
//   - z-halo comes from neighbor lanes via __shfl (lane == z4, the whole
//     z-row sits in one wave64), eliminating the 2 scalar halo loads.
//   - Output (768 MB, zero reuse) uses nontemporal stores so the streaming
//     writes don't write-allocate through L2 and evict the stencil planes.
//   Loads per output float4-triple: 7 -> ~3.1.

typedef float f32x4 __attribute__((ext_vector_type(4)));

__global__ __launch_bounds__(256) void fdgrad_kernel(
    const float* __restrict__ vin, float* __restrict__ vout) {
    const unsigned tid = blockIdx.x * 256u + threadIdx.x;

    const unsigned z4  = tid & 63u;          // float4 index along z (== lane)
    const unsigned y   = (tid >> 6) & 255u;
    const unsigned seg = (tid >> 14) & 15u;  // 16 x-segments of 16
    const unsigned b   = tid >> 18;

    const f32x4* __restrict__ vin4 = reinterpret_cast<const f32x4*>(vin);
    f32x4* __restrict__ vout4      = reinterpret_cast<f32x4*>(vout);

    const unsigned yp = (y + 1u) & 255u;
    const unsigned ym = (y + 255u) & 255u;

    const unsigned base_b = b << 22;
    const unsigned ofs_c  = (y  << 6) + z4;
    const unsigned ofs_yp = (yp << 6) + z4;
    const unsigned ofs_ym = (ym << 6) + z4;

    const unsigned out_gx = (b * 3u + 0u) << 22;
    const unsigned out_gy = (b * 3u + 1u) << 22;
    const unsigned out_gz = (b * 3u + 2u) << 22;

    const unsigned lane = threadIdx.x & 63u;
    const int lm = (int)((lane + 63u) & 63u);  // lane-1 (wraps: z periodic)
    const int lp = (int)((lane + 1u)  & 63u);  // lane+1

    unsigned x = seg << 4;

    // Sliding window prologue: vm = v[x-1], vc = v[x]
    f32x4 vm = vin4[base_b + (((x + 255u) & 255u) << 14) + ofs_c];
    f32x4 vc = vin4[base_b + (x << 14) + ofs_c];

#pragma unroll 4
    for (int i = 0; i < 16; ++i) {
        const unsigned xn = (x + 1u) & 255u;
        const f32x4 vp  = vin4[base_b + (xn << 14) + ofs_c];
        const f32x4 vyp = vin4[base_b + (x  << 14) + ofs_yp];
        const f32x4 vym = vin4[base_b + (x  << 14) + ofs_ym];

        // z halo from neighbor lanes: lane-1 holds v[z0-1] in .w,
        // lane+1 holds v[z0+4] in .x; wave wrap == periodic wrap.
        const float zm = __shfl(vc.w, lm, 64);
        const float zp = __shfl(vc.x, lp, 64);

        f32x4 gx, gy, gz;
        gx = (vp  - vm)  * 0.5f;
        gy = (vyp - vym) * 0.5f;
        gz.x = (vc.y - zm)   * 0.5f;
        gz.y = (vc.z - vc.x) * 0.5f;
        gz.z = (vc.w - vc.y) * 0.5f;
        gz.w = (zp   - vc.z) * 0.5f;

        const unsigned spatial = (x << 14) + ofs_c;
        __builtin_nontemporal_store(gx, &vout4[out_gx + spatial]);
        __builtin_nontemporal_store(gy, &vout4[out_gy + spatial]);
        __builtin_nontemporal_store(gz, &vout4[out_gz + spatial]);

        vm = vc;
        vc = vp;
        x  = xn;
    }
}

extern "C" void kernel_launch(void* const* d_in, const int* in_sizes, int n_in,
                              void* d_out, int out_size, void* d_ws, size_t ws_size,
                              hipStream_t stream) {
    const float* vin = (const float*)d_in[0];
    float* vout = (float*)d_out;
    // threads: 4 b * 16 seg * 256 y * 64 z4 = 1,048,576 -> 4096 blocks of 256
    fdgrad_kernel<<<4096, 256, 0, stream>>>(vin, vout);
}